// Round 1
// baseline (280.753 us; speedup 1.0000x reference)
//
#include <hip/hip_runtime.h>
#include <hip/hip_bf16.h>
#include <cstdint>

// Problem constants
#define TOK   64
#define INF   4096
#define OUTF  11008
#define KCHUNKS 128      // INF / 32
#define QCNT  8          // split-K factor -> K_block = 512
#define NCHB  172        // OUTF / 64 channels per block

using bf16x8  = __attribute__((ext_vector_type(8))) __bf16;
using floatx4 = __attribute__((ext_vector_type(4))) float;

union B8u { uint32_t u[4]; uint4 q; bf16x8 v; };

// pack two fp32 into one dword of two truncated bf16 (elem a = low half)
__device__ __forceinline__ uint32_t hi2(float a, float b) {
    return (__float_as_uint(a) >> 16) | (__float_as_uint(b) & 0xffff0000u);
}
// residual after bf16 truncation (exact in fp32)
__device__ __forceinline__ float losub(float x) {
    return x - __uint_as_float(__float_as_uint(x) & 0xffff0000u);
}
__device__ __forceinline__ void packW(float4 a, float4 b, B8u& wh, B8u& wl) {
    wh.u[0] = hi2(a.x, a.y);  wh.u[1] = hi2(a.z, a.w);
    wh.u[2] = hi2(b.x, b.y);  wh.u[3] = hi2(b.z, b.w);
    wl.u[0] = hi2(losub(a.x), losub(a.y));
    wl.u[1] = hi2(losub(a.z), losub(a.w));
    wl.u[2] = hi2(losub(b.x), losub(b.y));
    wl.u[3] = hi2(losub(b.z), losub(b.w));
}

// ---------------------------------------------------------------------------
// k_prep: MERGED prep_x + lora_t (one launch instead of two).
//  blocks 0..1023   : fp32 x -> bf16 hi/lo arrays in MFMA A-fragment order.
//  blocks 1024..1279: tm[t][r] = sum_k x[t][k]*A[r][k], one wave per (t,r).
// ---------------------------------------------------------------------------
__global__ __launch_bounds__(256) void k_prep(const float* __restrict__ x,
        const float* __restrict__ A,
        unsigned short* __restrict__ xh, unsigned short* __restrict__ xl,
        float* __restrict__ tm) {
    int b = blockIdx.x;
    if (b < 1024) {
        int idx  = b * 256 + threadIdx.x;                   // 0..262143
        int j    = idx & 7;
        int lane = (idx >> 3) & 63;
        int kc   = (idx >> 9) & 127;
        int mt   = idx >> 16;
        int row  = mt * 16 + (lane & 15);
        int col  = kc * 32 + ((lane >> 4) << 3) + j;
        float v  = x[(size_t)row * INF + col];
        float lo = losub(v);
        xh[idx] = (unsigned short)(__float_as_uint(v) >> 16);
        xl[idx] = (unsigned short)(__float_as_uint(lo) >> 16);
    } else {
        int bb   = b - 1024;                                // 0..255
        int t    = bb & 63;
        int wv   = threadIdx.x >> 6, lane = threadIdx.x & 63;
        int r    = (bb >> 6) * 4 + wv;
        const float4* xr = (const float4*)(x + (size_t)t * INF);
        const float4* ar = (const float4*)(A + (size_t)r * INF);
        float s = 0.f;
#pragma unroll
        for (int i = 0; i < INF / 4 / 64; ++i) {
            float4 a = xr[lane + i * 64], c = ar[lane + i * 64];
            s += a.x * c.x + a.y * c.y + a.z * c.z + a.w * c.w;
        }
#pragma unroll
        for (int off = 32; off > 0; off >>= 1) s += __shfl_down(s, off);
        if (lane == 0) tm[t * 16 + r] = s;
    }
}

// ---------------------------------------------------------------------------
// k_main: y = x @ W^T via 16x16x32 bf16 MFMA, fp32 emulated hi/lo:
//   x*w ~= xh*wh + xh*wl + xl*wh
// CHANGE vs previous round: double-buffered LDS slabs with phase size k=64
// (W 16KB + x 16KB per buffer, 64KB total -> still 2 blocks/CU) and ONE
// __syncthreads per phase instead of two.  Order per phase:
//   __syncthreads()          // built-in vmcnt(0) drain: phase p slab resident,
//                            // and all waves done reading buffer cur^1
//   stage(p+1 -> cur^1)      // prefetch issued BEFORE compute
//   compute(cur)             // MFMA under in-flight prefetch
// This removes the drain-with-no-lookahead stall: DMA for p+1 overlaps
// compute(p) within the block, on top of the 2-blocks/CU overlap.
// W keeps the per-row rotate swizzle (now mod-16 granules): DMA covers
// 4 rows x 256B dense per 1KB instruction; fragment reads <=2-way (free).
// ---------------------------------------------------------------------------
template<bool ATOMIC>
__global__ __launch_bounds__(256, 2) void k_main(const float* __restrict__ W,
        const uint4* __restrict__ xh, const uint4* __restrict__ xl,
        const float* __restrict__ scale, float* __restrict__ part,
        float* __restrict__ out) {
    // W slab: rows r=0..63, granules g=0..15 (16B each, k=64 floats/phase)
    // slot (r,g) holds global granule f=(g-r)&15 -> reader uses g=(f+r)&15
    __shared__ uint4 wlds[2][1024];   // 2 x 16 KB
    __shared__ uint4 xsl [2][1024];   // 2 x 16 KB: [hl][mt][kc 0..1][lane]

    int tid  = threadIdx.x;
    int lane = tid & 63;
    int wv   = tid >> 6;
    int quad = lane >> 4;
    int nb   = blockIdx.x % NCHB;
    int q    = blockIdx.x / NCHB;        // 0..QCNT-1
    int chl  = wv * 16 + (lane & 15);    // local channel row (0..63)
    int ch   = nb * 64 + chl;

    const int kbase = q * 512;           // starting k (floats) for this block
    int rr = lane >> 4;                  // row within a W DMA issue (0..3)
    int gg = lane & 15;                  // granule slot within row

    floatx4 acc[4] = {};

    auto stage = [&](int p, int bsel) {
        // ---- W slab: 16 issues of 1KB, each = 4 rows x 256B dense ----
#pragma unroll
        for (int t = 0; t < 4; ++t) {
            int i = wv * 4 + t;          // issue 0..15
            int r = i * 4 + rr;          // row 0..63
            int f = (gg - r) & 15;       // global granule (rotate swizzle)
            const float* src = W + (size_t)(nb * 64 + r) * INF
                             + kbase + p * 64 + f * 4;
            __builtin_amdgcn_global_load_lds(
                (const __attribute__((address_space(1))) uint32_t*)src,
                (__attribute__((address_space(3))) uint32_t*)&wlds[bsel][i * 64],
                16, 0, 0);
        }
        // ---- x slab: 16 issues of 1KB, contiguous in frag order ----
#pragma unroll
        for (int t = 0; t < 4; ++t) {
            int j  = wv * 4 + t;         // 0..15: [hl][mt][kc]
            int hl = j >> 3, mt = (j >> 1) & 3, kc = j & 1;
            const uint4* src = (hl ? xl : xh)
                + ((size_t)(mt * KCHUNKS + q * 16 + p * 2 + kc) * 64 + lane);
            __builtin_amdgcn_global_load_lds(
                (const __attribute__((address_space(1))) uint32_t*)src,
                (__attribute__((address_space(3))) uint32_t*)&xsl[bsel][j * 64],
                16, 0, 0);
        }
    };

    stage(0, 0);
    int cur = 0;
#pragma unroll
    for (int p = 0; p < 8; ++p) {
        __syncthreads();   // vmcnt(0) drain: slab p resident; cur^1 free to overwrite
        if (p < 7) stage(p + 1, cur ^ 1);

        // ---- compute 2 chunks (k=32 each) from buffer cur ----
#pragma unroll
        for (int kc = 0; kc < 2; ++kc) {
            int f0 = kc * 8 + quad * 2;
            uint4 wf0 = wlds[cur][chl * 16 + ((f0     + chl) & 15)];
            uint4 wf1 = wlds[cur][chl * 16 + ((f0 + 1 + chl) & 15)];
            B8u wh, wl;
            packW(*(float4*)&wf0, *(float4*)&wf1, wh, wl);
#pragma unroll
            for (int mt = 0; mt < 4; ++mt) {
                B8u ah, al;
                ah.q = xsl[cur][(    mt * 2 + kc) * 64 + lane];
                al.q = xsl[cur][(8 + mt * 2 + kc) * 64 + lane];
                acc[mt] = __builtin_amdgcn_mfma_f32_16x16x32_bf16(ah.v, wh.v, acc[mt], 0, 0, 0);
                acc[mt] = __builtin_amdgcn_mfma_f32_16x16x32_bf16(ah.v, wl.v, acc[mt], 0, 0, 0);
                acc[mt] = __builtin_amdgcn_mfma_f32_16x16x32_bf16(al.v, wh.v, acc[mt], 0, 0, 0);
            }
        }
        cur ^= 1;
    }

    // C/D layout (16x16, m89): col = lane&15 (= channel), row = quad*4 + reg (= token)
#pragma unroll
    for (int mt = 0; mt < 4; ++mt) {
        int token = mt * 16 + quad * 4;
#pragma unroll
        for (int r = 0; r < 4; ++r) {
            if constexpr (ATOMIC) {
                atomicAdd(&out[(size_t)(token + r) * OUTF + ch], scale[ch] * acc[mt][r]);
            } else {
                part[((size_t)q * TOK + token + r) * OUTF + ch] = acc[mt][r];
            }
        }
    }
}

// ---------------------------------------------------------------------------
// k_post: out[t][o] = scale[o]*sum_q part[q][t][o] + sum_r tm[t][r]*B[o][r] + bias[o]
// ---------------------------------------------------------------------------
__global__ __launch_bounds__(256) void k_post(const float* __restrict__ part,
        const float* __restrict__ scale, const float* __restrict__ bias,
        const float* __restrict__ lB, const float* __restrict__ tm,
        float* __restrict__ out) {
    int o = blockIdx.x * 256 + threadIdx.x;
    int t = blockIdx.y;
    if (o >= OUTF) return;
    float s = 0.f;
#pragma unroll
    for (int qq = 0; qq < QCNT; ++qq)
        s += part[((size_t)qq * TOK + t) * OUTF + o];
    const float4* Br = (const float4*)(lB + (size_t)o * 16);
    const float4* tr = (const float4*)(tm + (size_t)t * 16);
    float l = 0.f;
#pragma unroll
    for (int i = 0; i < 4; ++i) {
        float4 b = Br[i], tt = tr[i];
        l += b.x * tt.x + b.y * tt.y + b.z * tt.z + b.w * tt.w;
    }
    out[(size_t)t * OUTF + o] = s * scale[o] + l + bias[o];
}

// Fallback pre-init for the atomic path: out = lora + bias, main adds scale*y.
__global__ __launch_bounds__(256) void k_pre(const float* __restrict__ bias,
        const float* __restrict__ lB, const float* __restrict__ tm,
        float* __restrict__ out) {
    int o = blockIdx.x * 256 + threadIdx.x;
    int t = blockIdx.y;
    if (o >= OUTF) return;
    const float4* Br = (const float4*)(lB + (size_t)o * 16);
    const float4* tr = (const float4*)(tm + (size_t)t * 16);
    float l = 0.f;
#pragma unroll
    for (int i = 0; i < 4; ++i) {
        float4 b = Br[i], tt = tr[i];
        l += b.x * tt.x + b.y * tt.y + b.z * tt.z + b.w * tt.w;
    }
    out[(size_t)t * OUTF + o] = l + bias[o];
}

extern "C" void kernel_launch(void* const* d_in, const int* in_sizes, int n_in,
                              void* d_out, int out_size, void* d_ws, size_t ws_size,
                              hipStream_t stream) {
    const float* x     = (const float*)d_in[0];
    const float* W     = (const float*)d_in[1];
    const float* scale = (const float*)d_in[2];
    const float* lA    = (const float*)d_in[3];
    const float* lB    = (const float*)d_in[4];
    const float* bias  = (const float*)d_in[5];
    float* out = (float*)d_out;

    char* ws = (char*)d_ws;
    unsigned short* xh = (unsigned short*)(ws);            // 512 KB
    unsigned short* xl = (unsigned short*)(ws + 524288);   // 512 KB
    float* tm   = (float*)(ws + 1048576);                  // 4 KB
    float* part = (float*)(ws + 1052672);                  // 22.5 MB
    const size_t need = 1052672 + (size_t)QCNT * TOK * OUTF * 4;  // ~23.6 MB

    k_prep<<<1280, 256, 0, stream>>>(x, lA, xh, xl, tm);

    if (ws_size >= need) {
        k_main<false><<<NCHB * QCNT, 256, 0, stream>>>(W, (const uint4*)xh,
                (const uint4*)xl, scale, part, out);
        k_post<<<dim3(43, TOK), 256, 0, stream>>>(part, scale, bias, lB, tm, out);
    } else {
        k_pre<<<dim3(43, TOK), 256, 0, stream>>>(bias, lB, tm, out);
        k_main<true><<<NCHB * QCNT, 256, 0, stream>>>(W, (const uint4*)xh,
                (const uint4*)xl, scale, nullptr, out);
    }
}